// Round 2
// baseline (12751.425 us; speedup 1.0000x reference)
//
#include <hip/hip_runtime.h>
#include <math.h>

#define BB 128
#define TT 512
#define HH 128
#define G4 512      // 4*H
#define CC 128
#define WW 32

#define TEAMS 16    // batch groups (8 batches each)
#define WK    16    // workers (blocks) per team, each owns 8 hidden units
#define NBT   8     // batches per team
#define DD    4     // exchange ring depth

// ---- workspace layout (floats) ----
#define OFF_FCWT  0
#define OFF_H2A   (OFF_FCWT + CC*HH)        // [T][B][H], later y in-place
#define OFF_DOLD  (OFF_H2A + TT*BB*HH)
#define OFF_DH    (OFF_DOLD + TT*BB)
#define OFF_MT    (OFF_DH + TT*BB)
#define OFF_ST    (OFF_MT + TT)
#define OFF_EXH1  (OFF_ST + TT)             // DD*TEAMS*1024 each
#define OFF_EXC1  (OFF_EXH1 + DD*TEAMS*1024)
#define OFF_EXH2  (OFF_EXC1 + DD*TEAMS*1024)
#define OFF_FLAGS (OFF_EXH2 + DD*TEAMS*1024)  // ints: 2 * 256 * 16

__device__ __forceinline__ float sigm(float v) {
    return 1.f / (1.f + __expf(-v));
}
__device__ __forceinline__ float ftanh(float v) {
    return 1.f - 2.f / (__expf(2.f * v) + 1.f);
}

__device__ __forceinline__ void spin_ge(const int* fp, int target) {
    while (__hip_atomic_load(fp, __ATOMIC_RELAXED, __HIP_MEMORY_SCOPE_AGENT) < target) {
        __builtin_amdgcn_s_sleep(1);
    }
    (void)__hip_atomic_load(fp, __ATOMIC_ACQUIRE, __HIP_MEMORY_SCOPE_AGENT);
}

// K0: transpose fcW for coalesced K5 access
__global__ __launch_bounds__(256) void k0_prep(
    const float* __restrict__ fcW, float* __restrict__ fcWT)
{
    int idx = blockIdx.x * blockDim.x + threadIdx.x;
    if (idx < CC * HH) {
        int c = idx / HH, h = idx % HH;
        fcWT[h * CC + c] = fcW[idx];
    }
}

// K1: persistent distributed LSTM. 256 blocks = 16 teams x 16 workers.
// Worker owns 32 gate rows (8 hidden units x 4 gates) for its team's 8
// batches; weights LDS-resident; activations all-gathered via L2 each step.
__global__ __launch_bounds__(256) void k1_lstm(
    const float* __restrict__ x,
    const float* __restrict__ Wih1, const float* __restrict__ Whh1,
    const float* __restrict__ bih1, const float* __restrict__ bhh1,
    const float* __restrict__ Wih2, const float* __restrict__ Whh2,
    const float* __restrict__ bih2, const float* __restrict__ bhh2,
    float* __restrict__ h2a,
    float* __restrict__ exH1, float* __restrict__ exC1, float* __restrict__ exH2,
    int* __restrict__ flagsA, int* __restrict__ flagsB)
{
    __shared__ float w1s[32][132];   // pad->132: 8-row b128 reads conflict-free
    __shared__ float w2is[32][132];
    __shared__ float w2hs[32][132];
    __shared__ float h1f[NBT][132];
    __shared__ float c1f[NBT][132];
    __shared__ float h2f[NBT][132];
    __shared__ float gst[32][8];

    const int tid  = threadIdx.x;
    const int team = blockIdx.x & 15;   // team t -> XCD t%8 under %8 heuristic
    const int wkr  = blockIdx.x >> 4;
    const int b0   = team * NBT;
    const int lane = tid & 63;
    const int g    = tid >> 6;           // wave index == gate index 0..3
    const int j    = lane >> 3;          // local hidden 0..7
    const int bi   = lane & 7;           // batch within team
    const int r    = g * 8 + j;          // local row 0..31
    const int row  = g * 128 + wkr * 8 + j;  // global gate row 0..511

    // ---- stage weights into LDS (once) ----
    for (int idx = tid; idx < 32 * 32; idx += 256) {
        int rl = idx >> 5, q = idx & 31;
        int grow = (rl >> 3) * 128 + wkr * 8 + (rl & 7);
        float4 a = ((const float4*)(Whh1 + (size_t)grow * 128))[q];
        float4 b = ((const float4*)(Wih2 + (size_t)grow * 128))[q];
        float4 c = ((const float4*)(Whh2 + (size_t)grow * 128))[q];
        *(float4*)&w1s [rl][q * 4] = a;
        *(float4*)&w2is[rl][q * 4] = b;
        *(float4*)&w2hs[rl][q * 4] = c;
    }
    for (int idx = tid; idx < NBT * 132; idx += 256) {
        ((float*)h1f)[idx] = 0.f;
        ((float*)c1f)[idx] = 0.f;
        ((float*)h2f)[idx] = 0.f;
    }
    const float b1r  = bih1[row] + bhh1[row];
    const float b2r  = bih2[row] + bhh2[row];
    const float wi1r = Wih1[row];

    // cell-thread mapping (tid<64): cj = hidden-local, cb = batch
    const int cj = tid & 7, cb = tid >> 3;
    float c1reg = 0.f, c2reg = 0.f;

    int* myA = &flagsA[blockIdx.x * 16];
    int* myB = &flagsB[blockIdx.x * 16];
    __syncthreads();

    for (int t = 0; t < TT; ++t) {
        const int slot  = t & (DD - 1);
        const int slotP = (t - 1) & (DD - 1);

        // ---- phase A: layer-1 gates ----
        // peers' A(t-1) completion already guaranteed by our B(t-1) wait.
        if (t > 0) {
            const float4* src = (const float4*)(exH1 + ((size_t)(slotP * TEAMS + team) << 10));
            float4 v = src[tid];
            *(float4*)&h1f[tid >> 5][(tid & 31) * 4] = v;
            __syncthreads();
        }
        {
            float xv = x[(size_t)(b0 + bi) * TT + t];
            float acc = fmaf(xv, wi1r, b1r);
            const float4* wp = (const float4*)&w1s[r][0];
            const float4* hp = (const float4*)&h1f[bi][0];
            #pragma unroll 8
            for (int q = 0; q < 32; ++q) {
                float4 wv4 = wp[q], hv4 = hp[q];
                acc = fmaf(wv4.x, hv4.x, acc);
                acc = fmaf(wv4.y, hv4.y, acc);
                acc = fmaf(wv4.z, hv4.z, acc);
                acc = fmaf(wv4.w, hv4.w, acc);
            }
            gst[r][bi] = acc;
        }
        __syncthreads();
        if (tid < 64) {
            float gi = gst[0 * 8 + cj][cb], gf = gst[1 * 8 + cj][cb];
            float gg = gst[2 * 8 + cj][cb], go = gst[3 * 8 + cj][cb];
            float cn = sigm(gf) * c1reg + sigm(gi) * ftanh(gg);
            c1reg = cn;
            float hn = sigm(go) * ftanh(cn);
            size_t eo = ((size_t)(slot * TEAMS + team) << 10) + cb * 128 + wkr * 8 + cj;
            exH1[eo] = hn;
            exC1[eo] = cn;
        }
        __syncthreads();   // drains vmcnt: all exchange writes in flight done
        if (tid == 0) {
            __threadfence();
            __hip_atomic_store(myA, t + 1, __ATOMIC_RELEASE, __HIP_MEMORY_SCOPE_AGENT);
        }

        // ---- phase B: layer-2 gates (input = c1, recurrent = h2) ----
        if (tid < WK && tid != wkr)
            spin_ge(&flagsA[(tid * TEAMS + team) * 16], t + 1);
        if (t > 0 && tid >= 64 && tid < 64 + WK && (tid - 64) != wkr)
            spin_ge(&flagsB[((tid - 64) * TEAMS + team) * 16], t);
        __syncthreads();
        {
            const float4* srcC = (const float4*)(exC1 + ((size_t)(slot * TEAMS + team) << 10));
            float4 v = srcC[tid];
            *(float4*)&c1f[tid >> 5][(tid & 31) * 4] = v;
            if (t > 0) {
                const float4* srcH = (const float4*)(exH2 + ((size_t)(slotP * TEAMS + team) << 10));
                float4 u = srcH[tid];
                *(float4*)&h2f[tid >> 5][(tid & 31) * 4] = u;
            }
        }
        __syncthreads();
        {
            float acc = b2r;
            const float4* wip = (const float4*)&w2is[r][0];
            const float4* whp = (const float4*)&w2hs[r][0];
            const float4* cp  = (const float4*)&c1f[bi][0];
            const float4* hp  = (const float4*)&h2f[bi][0];
            #pragma unroll 4
            for (int q = 0; q < 32; ++q) {
                float4 a4 = wip[q], c4 = cp[q];
                float4 b4 = whp[q], h4 = hp[q];
                acc = fmaf(a4.x, c4.x, acc); acc = fmaf(b4.x, h4.x, acc);
                acc = fmaf(a4.y, c4.y, acc); acc = fmaf(b4.y, h4.y, acc);
                acc = fmaf(a4.z, c4.z, acc); acc = fmaf(b4.z, h4.z, acc);
                acc = fmaf(a4.w, c4.w, acc); acc = fmaf(b4.w, h4.w, acc);
            }
            gst[r][bi] = acc;
        }
        __syncthreads();
        if (tid < 64) {
            float gi = gst[0 * 8 + cj][cb], gf = gst[1 * 8 + cj][cb];
            float gg = gst[2 * 8 + cj][cb], go = gst[3 * 8 + cj][cb];
            float cn = sigm(gf) * c2reg + sigm(gi) * ftanh(gg);
            c2reg = cn;
            float hn = sigm(go) * ftanh(cn);
            exH2[((size_t)(slot * TEAMS + team) << 10) + cb * 128 + wkr * 8 + cj] = hn;
            h2a[(size_t)t * (BB * HH) + (size_t)(b0 + cb) * HH + wkr * 8 + cj] = hn;
        }
        __syncthreads();
        if (tid == 0) {
            __threadfence();
            __hip_atomic_store(myB, t + 1, __ATOMIC_RELEASE, __HIP_MEMORY_SCOPE_AGENT);
        }
    }
}

// K2: d_old[t,b] = h2[t,b,:].wt_old ; d_h[t,b] = h2[t,b,:].wt_h
__global__ __launch_bounds__(256) void k2_dots(
    const float* __restrict__ h2a, const float* __restrict__ w_t,
    float* __restrict__ dold, float* __restrict__ dh)
{
    const int lane = threadIdx.x & 63;
    const int wave = blockIdx.x * (blockDim.x >> 6) + (threadIdx.x >> 6);
    const int nw = gridDim.x * (blockDim.x >> 6);
    const float wh0 = w_t[lane],       wh1 = w_t[64 + lane];
    const float wo0 = w_t[128 + lane], wo1 = w_t[192 + lane];
    for (int row = wave; row < TT * BB; row += nw) {
        const float* p = h2a + (size_t)row * HH;
        float v0 = p[lane], v1 = p[64 + lane];
        float po = v0 * wo0 + v1 * wo1;
        float ph = v0 * wh0 + v1 * wh1;
        #pragma unroll
        for (int off = 32; off; off >>= 1) {
            po += __shfl_xor(po, off);
            ph += __shfl_xor(ph, off);
        }
        if (lane == 0) { dold[row] = po; dh[row] = ph; }
    }
}

// K3: per-t global softmax stats over valid (j,b): m[t], s[t]
__global__ __launch_bounds__(256) void k3_stats(
    const float* __restrict__ dold, const float* __restrict__ dh,
    float* __restrict__ mt, float* __restrict__ st)
{
    const int t = blockIdx.x;
    const int tid = threadIdx.x;
    const int cnt = (min(t, WW) + 1) * BB;
    const int jstart = max(t - (WW + 1), -1);

    float m = -INFINITY;
    for (int idx = tid; idx < cnt; idx += 256) {
        int jj = idx >> 7, b = idx & 127;
        int j = jstart + jj;
        float sc = dh[t * BB + b] + (j >= 0 ? dold[j * BB + b] : 0.f);
        m = fmaxf(m, sc);
    }
    #pragma unroll
    for (int off = 32; off; off >>= 1) m = fmaxf(m, __shfl_xor(m, off));
    __shared__ float rbuf[4];
    int wv = tid >> 6, ln = tid & 63;
    if (ln == 0) rbuf[wv] = m;
    __syncthreads();
    m = fmaxf(fmaxf(rbuf[0], rbuf[1]), fmaxf(rbuf[2], rbuf[3]));

    float s = 0.f;
    for (int idx = tid; idx < cnt; idx += 256) {
        int jj = idx >> 7, b = idx & 127;
        int j = jstart + jj;
        float sc = dh[t * BB + b] + (j >= 0 ? dold[j * BB + b] : 0.f);
        s += __expf(sc - m);
    }
    #pragma unroll
    for (int off = 32; off; off >>= 1) s += __shfl_xor(s, off);
    __shared__ float sbuf[4];
    if (ln == 0) sbuf[wv] = s;
    __syncthreads();
    if (tid == 0) { mt[t] = m; st[t] = sbuf[0] + sbuf[1] + sbuf[2] + sbuf[3]; }
}

// K4: attention + y = h2 + attn, written IN-PLACE over h2a.
__global__ __launch_bounds__(128) void k4_attn(
    float* __restrict__ h2a,
    const float* __restrict__ dold, const float* __restrict__ dh,
    const float* __restrict__ mt, const float* __restrict__ st)
{
    const int b = blockIdx.x;
    const int h = threadIdx.x;
    __shared__ float ring[33][HH];
    __shared__ float wj[33];

    #pragma unroll
    for (int s_ = 0; s_ < 33; ++s_) ring[s_][h] = 0.f;
    __syncthreads();

    for (int t = 0; t < TT; ++t) {
        float hv = h2a[(size_t)t * (BB * HH) + b * HH + h];
        if (h < 33) {
            int j = t - 33 + h;
            float w = 0.f;
            if (j >= 0)
                w = __expf(dold[j * BB + b] + dh[t * BB + b] - mt[t]) / st[t];
            wj[h] = w;
        }
        __syncthreads();

        float acc = 0.f;
        const int r0 = t % 33;
        #pragma unroll
        for (int jj = 0; jj < 33; ++jj) {
            int rr = r0 + jj; if (rr >= 33) rr -= 33;
            acc = fmaf(wj[jj], ring[rr][h], acc);
        }
        __syncthreads();

        h2a[(size_t)t * (BB * HH) + b * HH + h] = hv + acc;
        ring[r0][h] = hv;
    }
}

// K5: out[b,t,c] = y[t,b,:].fcW[c,:] + fcb[c]
__global__ __launch_bounds__(256) void k5_fc(
    const float* __restrict__ y, const float* __restrict__ fcWT,
    const float* __restrict__ fcb, float* __restrict__ out)
{
    const int t  = blockIdx.x;
    const int b0 = blockIdx.y * 32;
    const int tid = threadIdx.x;
    __shared__ float ytile[32][HH];

    for (int i = tid; i < 32 * HH; i += 256) {
        int rr = i >> 7, hh = i & 127;
        ytile[rr][hh] = y[(size_t)t * (BB * HH) + (b0 + rr) * HH + hh];
    }
    __syncthreads();

    const int c  = tid & 127;
    const int rh = tid >> 7;
    float acc[16];
    const float bias = fcb[c];
    #pragma unroll
    for (int rr = 0; rr < 16; ++rr) acc[rr] = bias;

    for (int hh = 0; hh < HH; ++hh) {
        float w = fcWT[hh * CC + c];
        #pragma unroll
        for (int rr = 0; rr < 16; ++rr)
            acc[rr] = fmaf(ytile[rh * 16 + rr][hh], w, acc[rr]);
    }
    #pragma unroll
    for (int rr = 0; rr < 16; ++rr) {
        int b = b0 + rh * 16 + rr;
        out[(size_t)b * (TT * CC) + t * CC + c] = acc[rr];
    }
}

extern "C" void kernel_launch(void* const* d_in, const int* in_sizes, int n_in,
                              void* d_out, int out_size, void* d_ws, size_t ws_size,
                              hipStream_t stream)
{
    const float* x    = (const float*)d_in[0];
    const float* Wih1 = (const float*)d_in[1];
    const float* Whh1 = (const float*)d_in[2];
    const float* bih1 = (const float*)d_in[3];
    const float* bhh1 = (const float*)d_in[4];
    const float* Wih2 = (const float*)d_in[5];
    const float* Whh2 = (const float*)d_in[6];
    const float* bih2 = (const float*)d_in[7];
    const float* bhh2 = (const float*)d_in[8];
    const float* w_t  = (const float*)d_in[9];
    const float* fcW  = (const float*)d_in[10];
    const float* fcb  = (const float*)d_in[11];
    float* out = (float*)d_out;

    float* ws   = (float*)d_ws;
    float* fcWT = ws + OFF_FCWT;
    float* h2a  = ws + OFF_H2A;
    float* dold = ws + OFF_DOLD;
    float* dh   = ws + OFF_DH;
    float* mt   = ws + OFF_MT;
    float* st   = ws + OFF_ST;
    float* exH1 = ws + OFF_EXH1;
    float* exC1 = ws + OFF_EXC1;
    float* exH2 = ws + OFF_EXH2;
    int*   flagsA = (int*)(ws + OFF_FLAGS);
    int*   flagsB = flagsA + 256 * 16;

    // zero the sync flags (harness re-poisons ws before every launch)
    hipMemsetAsync((void*)flagsA, 0, 2 * 256 * 16 * sizeof(int), stream);

    k0_prep<<<dim3((CC * HH + 255) / 256), dim3(256), 0, stream>>>(fcW, fcWT);

    k1_lstm<<<dim3(TEAMS * WK), dim3(256), 0, stream>>>(
        x, Wih1, Whh1, bih1, bhh1, Wih2, Whh2, bih2, bhh2,
        h2a, exH1, exC1, exH2, flagsA, flagsB);

    k2_dots<<<dim3(256), dim3(256), 0, stream>>>(h2a, w_t, dold, dh);

    k3_stats<<<dim3(TT), dim3(256), 0, stream>>>(dold, dh, mt, st);

    k4_attn<<<dim3(BB), dim3(128), 0, stream>>>(h2a, dold, dh, mt, st);

    k5_fc<<<dim3(TT, BB / 32), dim3(256), 0, stream>>>(h2a, fcWT, fcb, out);
}

// Round 3
// 7444.339 us; speedup vs baseline: 1.7129x; 1.7129x over previous
//
#include <hip/hip_runtime.h>
#include <math.h>

#define BB 128
#define TT 512
#define HH 128
#define G4 512      // 4*H
#define CC 128
#define WW 32

// ---- workspace layout (floats) ----
#define OFF_FCWT  0
#define OFF_H2A   (OFF_FCWT + CC*HH)        // [T][B][H], later y in-place
#define OFF_DOLD  (OFF_H2A + TT*BB*HH)
#define OFF_DH    (OFF_DOLD + TT*BB)
#define OFF_MT    (OFF_DH + TT*BB)
#define OFF_ST    (OFF_MT + TT)

__device__ __forceinline__ float sigm(float v) {
    return 1.f / (1.f + __expf(-v));
}
__device__ __forceinline__ float ftanh(float v) {
    return 1.f - 2.f / (__expf(2.f * v) + 1.f);
}

// K0: transpose fcW for coalesced K5 access
__global__ __launch_bounds__(256) void k0_prep(
    const float* __restrict__ fcW, float* __restrict__ fcWT)
{
    int idx = blockIdx.x * blockDim.x + threadIdx.x;
    if (idx < CC * HH) {
        int c = idx / HH, h = idx % HH;
        fcWT[h * CC + c] = fcW[idx];
    }
}

// K1: register-resident-weight LSTM. 128 blocks (1 batch each) x 512 threads.
// Thread j permanently holds row j of Whh1, Wih2, Whh2 in VGPRs (384 regs).
// h/c1/h2 broadcast via LDS (same-address float4 reads -> conflict-free).
// No cross-block communication of any kind.
__global__ __launch_bounds__(512, 1) void k1_lstm(
    const float* __restrict__ x,
    const float* __restrict__ Wih1, const float* __restrict__ Whh1,
    const float* __restrict__ bih1, const float* __restrict__ bhh1,
    const float* __restrict__ Wih2, const float* __restrict__ Whh2,
    const float* __restrict__ bih2, const float* __restrict__ bhh2,
    float* __restrict__ h2a)
{
    __shared__ float h1f[HH];
    __shared__ float c1f[HH];
    __shared__ float h2f[HH];
    __shared__ float gst[G4];
    __shared__ float xs[TT];

    const int j = threadIdx.x;   // gate row 0..511
    const int b = blockIdx.x;    // batch

    // ---- one-time: row j of each weight matrix into registers ----
    float w1r[HH], wi2r[HH], wh2r[HH];
    {
        const float4* p1 = (const float4*)(Whh1 + (size_t)j * HH);
        const float4* p2 = (const float4*)(Wih2 + (size_t)j * HH);
        const float4* p3 = (const float4*)(Whh2 + (size_t)j * HH);
        #pragma unroll
        for (int q = 0; q < HH / 4; ++q) {
            float4 a = p1[q], c = p2[q], d = p3[q];
            w1r [4*q+0] = a.x; w1r [4*q+1] = a.y; w1r [4*q+2] = a.z; w1r [4*q+3] = a.w;
            wi2r[4*q+0] = c.x; wi2r[4*q+1] = c.y; wi2r[4*q+2] = c.z; wi2r[4*q+3] = c.w;
            wh2r[4*q+0] = d.x; wh2r[4*q+1] = d.y; wh2r[4*q+2] = d.z; wh2r[4*q+3] = d.w;
        }
    }
    const float b1r  = bih1[j] + bhh1[j];
    const float b2r  = bih2[j] + bhh2[j];
    const float wi1r = Wih1[j];

    xs[j] = x[(size_t)b * TT + j];              // 512 threads cover T=512
    if (j < HH) { h1f[j] = 0.f; c1f[j] = 0.f; h2f[j] = 0.f; }
    float c1reg = 0.f, c2reg = 0.f;             // live only for j < 128
    __syncthreads();

    for (int t = 0; t < TT; ++t) {
        // ---- layer-1 gate row j ----
        {
            float acc = fmaf(xs[t], wi1r, b1r);
            #pragma unroll
            for (int q = 0; q < HH / 4; ++q) {
                float4 hv = *(const float4*)&h1f[4 * q];   // broadcast read
                acc = fmaf(w1r[4*q+0], hv.x, acc);
                acc = fmaf(w1r[4*q+1], hv.y, acc);
                acc = fmaf(w1r[4*q+2], hv.z, acc);
                acc = fmaf(w1r[4*q+3], hv.w, acc);
            }
            gst[j] = acc;
        }
        __syncthreads();                         // A: gates1 done
        if (j < HH) {
            float gi = gst[j], gf = gst[HH + j];
            float gg = gst[2*HH + j], go = gst[3*HH + j];
            float cn = sigm(gf) * c1reg + sigm(gi) * ftanh(gg);
            c1reg = cn;
            float hn = sigm(go) * ftanh(cn);
            c1f[j] = cn;                         // layer-2 input
            h1f[j] = hn;                         // next-step layer-1 recurrent
        }
        __syncthreads();                         // B: cell1 done, gst free

        // ---- layer-2 gate row j (input c1, recurrent h2) ----
        {
            float acc = b2r;
            #pragma unroll
            for (int q = 0; q < HH / 4; ++q) {
                float4 cv = *(const float4*)&c1f[4 * q];   // broadcast
                float4 hv = *(const float4*)&h2f[4 * q];   // broadcast
                acc = fmaf(wi2r[4*q+0], cv.x, acc); acc = fmaf(wh2r[4*q+0], hv.x, acc);
                acc = fmaf(wi2r[4*q+1], cv.y, acc); acc = fmaf(wh2r[4*q+1], hv.y, acc);
                acc = fmaf(wi2r[4*q+2], cv.z, acc); acc = fmaf(wh2r[4*q+2], hv.z, acc);
                acc = fmaf(wi2r[4*q+3], cv.w, acc); acc = fmaf(wh2r[4*q+3], hv.w, acc);
            }
            gst[j] = acc;
        }
        __syncthreads();                         // C: gates2 done
        if (j < HH) {
            float gi = gst[j], gf = gst[HH + j];
            float gg = gst[2*HH + j], go = gst[3*HH + j];
            float cn = sigm(gf) * c2reg + sigm(gi) * ftanh(gg);
            c2reg = cn;
            float hn = sigm(go) * ftanh(cn);
            h2f[j] = hn;
            h2a[(size_t)t * (BB * HH) + (size_t)b * HH + j] = hn;
        }
        __syncthreads();                         // D: cell2 done, gst/h2f safe
    }
}

// K2: d_old[t,b] = h2[t,b,:].wt_old ; d_h[t,b] = h2[t,b,:].wt_h
__global__ __launch_bounds__(256) void k2_dots(
    const float* __restrict__ h2a, const float* __restrict__ w_t,
    float* __restrict__ dold, float* __restrict__ dh)
{
    const int lane = threadIdx.x & 63;
    const int wave = blockIdx.x * (blockDim.x >> 6) + (threadIdx.x >> 6);
    const int nw = gridDim.x * (blockDim.x >> 6);
    const float wh0 = w_t[lane],       wh1 = w_t[64 + lane];
    const float wo0 = w_t[128 + lane], wo1 = w_t[192 + lane];
    for (int row = wave; row < TT * BB; row += nw) {
        const float* p = h2a + (size_t)row * HH;
        float v0 = p[lane], v1 = p[64 + lane];
        float po = v0 * wo0 + v1 * wo1;
        float ph = v0 * wh0 + v1 * wh1;
        #pragma unroll
        for (int off = 32; off; off >>= 1) {
            po += __shfl_xor(po, off);
            ph += __shfl_xor(ph, off);
        }
        if (lane == 0) { dold[row] = po; dh[row] = ph; }
    }
}

// K3: per-t global softmax stats over valid (j,b): m[t], s[t]
__global__ __launch_bounds__(256) void k3_stats(
    const float* __restrict__ dold, const float* __restrict__ dh,
    float* __restrict__ mt, float* __restrict__ st)
{
    const int t = blockIdx.x;
    const int tid = threadIdx.x;
    const int cnt = (min(t, WW) + 1) * BB;
    const int jstart = max(t - (WW + 1), -1);

    float m = -INFINITY;
    for (int idx = tid; idx < cnt; idx += 256) {
        int jj = idx >> 7, b = idx & 127;
        int j = jstart + jj;
        float sc = dh[t * BB + b] + (j >= 0 ? dold[j * BB + b] : 0.f);
        m = fmaxf(m, sc);
    }
    #pragma unroll
    for (int off = 32; off; off >>= 1) m = fmaxf(m, __shfl_xor(m, off));
    __shared__ float rbuf[4];
    int wv = tid >> 6, ln = tid & 63;
    if (ln == 0) rbuf[wv] = m;
    __syncthreads();
    m = fmaxf(fmaxf(rbuf[0], rbuf[1]), fmaxf(rbuf[2], rbuf[3]));

    float s = 0.f;
    for (int idx = tid; idx < cnt; idx += 256) {
        int jj = idx >> 7, b = idx & 127;
        int j = jstart + jj;
        float sc = dh[t * BB + b] + (j >= 0 ? dold[j * BB + b] : 0.f);
        s += __expf(sc - m);
    }
    #pragma unroll
    for (int off = 32; off; off >>= 1) s += __shfl_xor(s, off);
    __shared__ float sbuf[4];
    if (ln == 0) sbuf[wv] = s;
    __syncthreads();
    if (tid == 0) { mt[t] = m; st[t] = sbuf[0] + sbuf[1] + sbuf[2] + sbuf[3]; }
}

// K4: attention + y = h2 + attn, written IN-PLACE over h2a.
__global__ __launch_bounds__(128) void k4_attn(
    float* __restrict__ h2a,
    const float* __restrict__ dold, const float* __restrict__ dh,
    const float* __restrict__ mt, const float* __restrict__ st)
{
    const int b = blockIdx.x;
    const int h = threadIdx.x;
    __shared__ float ring[33][HH];
    __shared__ float wj[33];

    #pragma unroll
    for (int s_ = 0; s_ < 33; ++s_) ring[s_][h] = 0.f;
    __syncthreads();

    for (int t = 0; t < TT; ++t) {
        float hv = h2a[(size_t)t * (BB * HH) + b * HH + h];
        if (h < 33) {
            int j = t - 33 + h;
            float w = 0.f;
            if (j >= 0)
                w = __expf(dold[j * BB + b] + dh[t * BB + b] - mt[t]) / st[t];
            wj[h] = w;
        }
        __syncthreads();

        float acc = 0.f;
        const int r0 = t % 33;
        #pragma unroll
        for (int jj = 0; jj < 33; ++jj) {
            int rr = r0 + jj; if (rr >= 33) rr -= 33;
            acc = fmaf(wj[jj], ring[rr][h], acc);
        }
        __syncthreads();

        h2a[(size_t)t * (BB * HH) + b * HH + h] = hv + acc;
        ring[r0][h] = hv;
    }
}

// K5: out[b,t,c] = y[t,b,:].fcW[c,:] + fcb[c]
__global__ __launch_bounds__(256) void k5_fc(
    const float* __restrict__ y, const float* __restrict__ fcWT,
    const float* __restrict__ fcb, float* __restrict__ out)
{
    const int t  = blockIdx.x;
    const int b0 = blockIdx.y * 32;
    const int tid = threadIdx.x;
    __shared__ float ytile[32][HH];

    for (int i = tid; i < 32 * HH; i += 256) {
        int rr = i >> 7, hh = i & 127;
        ytile[rr][hh] = y[(size_t)t * (BB * HH) + (b0 + rr) * HH + hh];
    }
    __syncthreads();

    const int c  = tid & 127;
    const int rh = tid >> 7;
    float acc[16];
    const float bias = fcb[c];
    #pragma unroll
    for (int rr = 0; rr < 16; ++rr) acc[rr] = bias;

    for (int hh = 0; hh < HH; ++hh) {
        float w = fcWT[hh * CC + c];
        #pragma unroll
        for (int rr = 0; rr < 16; ++rr)
            acc[rr] = fmaf(ytile[rh * 16 + rr][hh], w, acc[rr]);
    }
    #pragma unroll
    for (int rr = 0; rr < 16; ++rr) {
        int b = b0 + rh * 16 + rr;
        out[(size_t)b * (TT * CC) + t * CC + c] = acc[rr];
    }
}

extern "C" void kernel_launch(void* const* d_in, const int* in_sizes, int n_in,
                              void* d_out, int out_size, void* d_ws, size_t ws_size,
                              hipStream_t stream)
{
    const float* x    = (const float*)d_in[0];
    const float* Wih1 = (const float*)d_in[1];
    const float* Whh1 = (const float*)d_in[2];
    const float* bih1 = (const float*)d_in[3];
    const float* bhh1 = (const float*)d_in[4];
    const float* Wih2 = (const float*)d_in[5];
    const float* Whh2 = (const float*)d_in[6];
    const float* bih2 = (const float*)d_in[7];
    const float* bhh2 = (const float*)d_in[8];
    const float* w_t  = (const float*)d_in[9];
    const float* fcW  = (const float*)d_in[10];
    const float* fcb  = (const float*)d_in[11];
    float* out = (float*)d_out;

    float* ws   = (float*)d_ws;
    float* fcWT = ws + OFF_FCWT;
    float* h2a  = ws + OFF_H2A;
    float* dold = ws + OFF_DOLD;
    float* dh   = ws + OFF_DH;
    float* mt   = ws + OFF_MT;
    float* st   = ws + OFF_ST;

    k0_prep<<<dim3((CC * HH + 255) / 256), dim3(256), 0, stream>>>(fcW, fcWT);

    k1_lstm<<<dim3(BB), dim3(512), 0, stream>>>(
        x, Wih1, Whh1, bih1, bhh1, Wih2, Whh2, bih2, bhh2, h2a);

    k2_dots<<<dim3(256), dim3(256), 0, stream>>>(h2a, w_t, dold, dh);

    k3_stats<<<dim3(TT), dim3(256), 0, stream>>>(dold, dh, mt, st);

    k4_attn<<<dim3(BB), dim3(128), 0, stream>>>(h2a, dold, dh, mt, st);

    k5_fc<<<dim3(TT, BB / 32), dim3(256), 0, stream>>>(h2a, fcWT, fcb, out);
}

// Round 4
// 1534.857 us; speedup vs baseline: 8.3079x; 4.8502x over previous
//
#include <hip/hip_runtime.h>
#include <math.h>

#define BB 128
#define TT 512
#define HH 128
#define G4 512      // 4*H
#define CC 128
#define WW 32

// ---- workspace layout (float slots) ----
#define OFF_FCWT  0                          // 16384
#define OFF_W1H   (OFF_FCWT + CC*HH)         // f16 Whh1: 65536 halves = 32768 slots
#define OFF_WI2H  (OFF_W1H  + G4*HH/2)
#define OFF_WH2H  (OFF_WI2H + G4*HH/2)
#define OFF_H2A   (OFF_WH2H + G4*HH/2)       // [T][B][H] fp32, later y in-place
#define OFF_DOLD  (OFF_H2A + TT*BB*HH)
#define OFF_DH    (OFF_DOLD + TT*BB)
#define OFF_MT    (OFF_DH + TT*BB)
#define OFF_ST    (OFF_MT + TT)

// k1 dynamic LDS carve (uint words)
#define PW        68                         // padded words per f16 row (16B-aligned)
#define L_W1      0                          // 512*68 = 34816 words
#define L_H1H     34816                      // 64 words (128 halves)
#define L_C1H     34880
#define L_H2H     34944
#define L_GST     35008                      // 512 floats
#define L_XS      35520                      // 512 floats
#define K1_LDS_B  (36032 * 4)                // 144128 bytes

typedef _Float16 h2t __attribute__((ext_vector_type(2)));

__device__ __forceinline__ float sigm(float v) {
    return 1.f / (1.f + __expf(-v));
}
__device__ __forceinline__ float ftanh(float v) {
    return 1.f - 2.f / (__expf(2.f * v) + 1.f);
}

__device__ __forceinline__ float dot2f(unsigned int a, unsigned int b, float acc) {
#if defined(__has_builtin) && __has_builtin(__builtin_amdgcn_fdot2)
    return __builtin_amdgcn_fdot2(__builtin_bit_cast(h2t, a),
                                  __builtin_bit_cast(h2t, b), acc, false);
#else
    h2t av = __builtin_bit_cast(h2t, a), bv = __builtin_bit_cast(h2t, b);
    acc = fmaf((float)av.x, (float)bv.x, acc);
    acc = fmaf((float)av.y, (float)bv.y, acc);
    return acc;
#endif
}

// K0: transpose fcW (fp32) + emit f16 images of Whh1, Wih2, Whh2
__global__ __launch_bounds__(256) void k0_prep(
    const float* __restrict__ Whh1, const float* __restrict__ Wih2,
    const float* __restrict__ Whh2, const float* __restrict__ fcW,
    float* __restrict__ fcWT,
    unsigned short* __restrict__ w1h, unsigned short* __restrict__ wi2h,
    unsigned short* __restrict__ wh2h)
{
    int idx = blockIdx.x * blockDim.x + threadIdx.x;
    if (idx < G4 * HH) {
        w1h [idx] = __builtin_bit_cast(unsigned short, (_Float16)Whh1[idx]);
        wi2h[idx] = __builtin_bit_cast(unsigned short, (_Float16)Wih2[idx]);
        wh2h[idx] = __builtin_bit_cast(unsigned short, (_Float16)Whh2[idx]);
    }
    if (idx < CC * HH) {
        int c = idx / HH, h = idx % HH;
        fcWT[h * CC + c] = fcW[idx];
    }
}

// K1: fully on-chip-weight LSTM. 128 blocks (1 batch) x 512 threads.
// Whh1 (f16) in LDS; Wih2/Whh2 rows (f16 packed) in 128 VGPRs/thread.
// fp32 cell state in regs; f16 only across the gate matmuls (v_dot2_f32_f16).
__global__ __launch_bounds__(512, 2) void k1_lstm(
    const float* __restrict__ x,
    const float* __restrict__ Wih1,
    const float* __restrict__ bih1, const float* __restrict__ bhh1,
    const float* __restrict__ bih2, const float* __restrict__ bhh2,
    const unsigned short* __restrict__ w1h,
    const unsigned short* __restrict__ wi2h,
    const unsigned short* __restrict__ wh2h,
    float* __restrict__ h2a)
{
    extern __shared__ unsigned int sm[];
    unsigned int* whh1s = sm + L_W1;
    unsigned int* h1h   = sm + L_H1H;
    unsigned int* c1h   = sm + L_C1H;
    unsigned int* h2h   = sm + L_H2H;
    float*        gst   = (float*)(sm + L_GST);
    float*        xs    = (float*)(sm + L_XS);

    const int j = threadIdx.x;   // gate row 0..511
    const int b = blockIdx.x;    // batch

    // ---- stage Whh1 f16 into padded LDS (one-time) ----
    {
        const uint4* src = (const uint4*)w1h;            // 512 rows x 16 uint4
        for (int i = j; i < 512 * 16; i += 512) {
            int r = i >> 4, q = i & 15;
            uint4 v = src[i];
            *(uint4*)&whh1s[r * PW + q * 4] = v;
        }
    }
    // ---- row j of Wih2 / Whh2 into registers (32 x uint4 = 128 VGPRs) ----
    uint4 wi2[16], wh2[16];
    {
        const uint4* p2 = (const uint4*)(wi2h + (size_t)j * HH);
        const uint4* p3 = (const uint4*)(wh2h + (size_t)j * HH);
        #pragma unroll
        for (int q = 0; q < 16; ++q) { wi2[q] = p2[q]; wh2[q] = p3[q]; }
    }
    const float b1r  = bih1[j] + bhh1[j];
    const float b2r  = bih2[j] + bhh2[j];
    const float wi1r = Wih1[j];

    xs[j] = x[(size_t)b * TT + j];
    if (j < 64) { h1h[j] = 0u; c1h[j] = 0u; h2h[j] = 0u; }
    float c1reg = 0.f, c2reg = 0.f;      // live for j < 128
    __syncthreads();

    for (int t = 0; t < TT; ++t) {
        // ---- layer-1 gate row j ----
        {
            float acc = fmaf(xs[t], wi1r, b1r);
            const uint4* wr = (const uint4*)&whh1s[j * PW];
            #pragma unroll
            for (int q = 0; q < 16; ++q) {
                uint4 wv = wr[q];
                uint4 hv = *(const uint4*)&h1h[q * 4];    // broadcast
                acc = dot2f(wv.x, hv.x, acc);
                acc = dot2f(wv.y, hv.y, acc);
                acc = dot2f(wv.z, hv.z, acc);
                acc = dot2f(wv.w, hv.w, acc);
            }
            gst[j] = acc;
        }
        __syncthreads();                                  // A: gates1 done
        if (j < HH) {
            float gi = gst[j], gf = gst[HH + j];
            float gg = gst[2*HH + j], go = gst[3*HH + j];
            float cn = sigm(gf) * c1reg + sigm(gi) * ftanh(gg);
            c1reg = cn;
            float hn = sigm(go) * ftanh(cn);
            ((unsigned short*)h1h)[j] = __builtin_bit_cast(unsigned short, (_Float16)hn);
            ((unsigned short*)c1h)[j] = __builtin_bit_cast(unsigned short, (_Float16)cn);
        }
        __syncthreads();                                  // B: cell1 done, gst free

        // ---- layer-2 gate row j (input c1, recurrent h2) ----
        {
            float acc = b2r;
            #pragma unroll
            for (int q = 0; q < 16; ++q) {
                uint4 cv = *(const uint4*)&c1h[q * 4];    // broadcast
                uint4 hv = *(const uint4*)&h2h[q * 4];    // broadcast
                acc = dot2f(wi2[q].x, cv.x, acc);
                acc = dot2f(wh2[q].x, hv.x, acc);
                acc = dot2f(wi2[q].y, cv.y, acc);
                acc = dot2f(wh2[q].y, hv.y, acc);
                acc = dot2f(wi2[q].z, cv.z, acc);
                acc = dot2f(wh2[q].z, hv.z, acc);
                acc = dot2f(wi2[q].w, cv.w, acc);
                acc = dot2f(wh2[q].w, hv.w, acc);
            }
            gst[j] = acc;
        }
        __syncthreads();                                  // C: gates2 done
        if (j < HH) {
            float gi = gst[j], gf = gst[HH + j];
            float gg = gst[2*HH + j], go = gst[3*HH + j];
            float cn = sigm(gf) * c2reg + sigm(gi) * ftanh(gg);
            c2reg = cn;
            float hn = sigm(go) * ftanh(cn);
            ((unsigned short*)h2h)[j] = __builtin_bit_cast(unsigned short, (_Float16)hn);
            h2a[(size_t)t * (BB * HH) + (size_t)b * HH + j] = hn;
        }
        __syncthreads();                                  // D: cell2 done
    }
}

// K2: d_old[t,b] = h2[t,b,:].wt_old ; d_h[t,b] = h2[t,b,:].wt_h
__global__ __launch_bounds__(256) void k2_dots(
    const float* __restrict__ h2a, const float* __restrict__ w_t,
    float* __restrict__ dold, float* __restrict__ dh)
{
    const int lane = threadIdx.x & 63;
    const int wave = blockIdx.x * (blockDim.x >> 6) + (threadIdx.x >> 6);
    const int nw = gridDim.x * (blockDim.x >> 6);
    const float wh0 = w_t[lane],       wh1 = w_t[64 + lane];
    const float wo0 = w_t[128 + lane], wo1 = w_t[192 + lane];
    for (int row = wave; row < TT * BB; row += nw) {
        const float* p = h2a + (size_t)row * HH;
        float v0 = p[lane], v1 = p[64 + lane];
        float po = v0 * wo0 + v1 * wo1;
        float ph = v0 * wh0 + v1 * wh1;
        #pragma unroll
        for (int off = 32; off; off >>= 1) {
            po += __shfl_xor(po, off);
            ph += __shfl_xor(ph, off);
        }
        if (lane == 0) { dold[row] = po; dh[row] = ph; }
    }
}

// K3: per-t global softmax stats over valid (j,b): m[t], s[t]
__global__ __launch_bounds__(256) void k3_stats(
    const float* __restrict__ dold, const float* __restrict__ dh,
    float* __restrict__ mt, float* __restrict__ st)
{
    const int t = blockIdx.x;
    const int tid = threadIdx.x;
    const int cnt = (min(t, WW) + 1) * BB;
    const int jstart = max(t - (WW + 1), -1);

    float m = -INFINITY;
    for (int idx = tid; idx < cnt; idx += 256) {
        int jj = idx >> 7, b = idx & 127;
        int j = jstart + jj;
        float sc = dh[t * BB + b] + (j >= 0 ? dold[j * BB + b] : 0.f);
        m = fmaxf(m, sc);
    }
    #pragma unroll
    for (int off = 32; off; off >>= 1) m = fmaxf(m, __shfl_xor(m, off));
    __shared__ float rbuf[4];
    int wv = tid >> 6, ln = tid & 63;
    if (ln == 0) rbuf[wv] = m;
    __syncthreads();
    m = fmaxf(fmaxf(rbuf[0], rbuf[1]), fmaxf(rbuf[2], rbuf[3]));

    float s = 0.f;
    for (int idx = tid; idx < cnt; idx += 256) {
        int jj = idx >> 7, b = idx & 127;
        int j = jstart + jj;
        float sc = dh[t * BB + b] + (j >= 0 ? dold[j * BB + b] : 0.f);
        s += __expf(sc - m);
    }
    #pragma unroll
    for (int off = 32; off; off >>= 1) s += __shfl_xor(s, off);
    __shared__ float sbuf[4];
    if (ln == 0) sbuf[wv] = s;
    __syncthreads();
    if (tid == 0) { mt[t] = m; st[t] = sbuf[0] + sbuf[1] + sbuf[2] + sbuf[3]; }
}

// K4: attention + y = h2 + attn, written IN-PLACE over h2a (sequential per
// batch; ring preloads history before overwrite -> in-place safe).
__global__ __launch_bounds__(128) void k4_attn(
    float* __restrict__ h2a,
    const float* __restrict__ dold, const float* __restrict__ dh,
    const float* __restrict__ mt, const float* __restrict__ st)
{
    const int b = blockIdx.x;
    const int h = threadIdx.x;
    __shared__ float ring[33][HH];
    __shared__ float wj[33];

    #pragma unroll
    for (int s_ = 0; s_ < 33; ++s_) ring[s_][h] = 0.f;
    __syncthreads();

    for (int t = 0; t < TT; ++t) {
        float hv = h2a[(size_t)t * (BB * HH) + b * HH + h];
        if (h < 33) {
            int j = t - 33 + h;
            float w = 0.f;
            if (j >= 0)
                w = __expf(dold[j * BB + b] + dh[t * BB + b] - mt[t]) / st[t];
            wj[h] = w;
        }
        __syncthreads();

        float acc = 0.f;
        const int r0 = t % 33;
        #pragma unroll
        for (int jj = 0; jj < 33; ++jj) {
            int rr = r0 + jj; if (rr >= 33) rr -= 33;
            acc = fmaf(wj[jj], ring[rr][h], acc);
        }
        __syncthreads();

        h2a[(size_t)t * (BB * HH) + b * HH + h] = hv + acc;
        ring[r0][h] = hv;
    }
}

// K5: out[b,t,c] = y[t,b,:].fcW[c,:] + fcb[c]
__global__ __launch_bounds__(256) void k5_fc(
    const float* __restrict__ y, const float* __restrict__ fcWT,
    const float* __restrict__ fcb, float* __restrict__ out)
{
    const int t  = blockIdx.x;
    const int b0 = blockIdx.y * 32;
    const int tid = threadIdx.x;
    __shared__ float ytile[32][HH];

    for (int i = tid; i < 32 * HH; i += 256) {
        int rr = i >> 7, hh = i & 127;
        ytile[rr][hh] = y[(size_t)t * (BB * HH) + (b0 + rr) * HH + hh];
    }
    __syncthreads();

    const int c  = tid & 127;
    const int rh = tid >> 7;
    float acc[16];
    const float bias = fcb[c];
    #pragma unroll
    for (int rr = 0; rr < 16; ++rr) acc[rr] = bias;

    for (int hh = 0; hh < HH; ++hh) {
        float w = fcWT[hh * CC + c];
        #pragma unroll
        for (int rr = 0; rr < 16; ++rr)
            acc[rr] = fmaf(ytile[rh * 16 + rr][hh], w, acc[rr]);
    }
    #pragma unroll
    for (int rr = 0; rr < 16; ++rr) {
        int b = b0 + rh * 16 + rr;
        out[(size_t)b * (TT * CC) + t * CC + c] = acc[rr];
    }
}

extern "C" void kernel_launch(void* const* d_in, const int* in_sizes, int n_in,
                              void* d_out, int out_size, void* d_ws, size_t ws_size,
                              hipStream_t stream)
{
    const float* x    = (const float*)d_in[0];
    const float* Wih1 = (const float*)d_in[1];
    const float* Whh1 = (const float*)d_in[2];
    const float* bih1 = (const float*)d_in[3];
    const float* bhh1 = (const float*)d_in[4];
    const float* Wih2 = (const float*)d_in[5];
    const float* Whh2 = (const float*)d_in[6];
    const float* bih2 = (const float*)d_in[7];
    const float* bhh2 = (const float*)d_in[8];
    const float* w_t  = (const float*)d_in[9];
    const float* fcW  = (const float*)d_in[10];
    const float* fcb  = (const float*)d_in[11];
    float* out = (float*)d_out;

    float* ws   = (float*)d_ws;
    float* fcWT = ws + OFF_FCWT;
    unsigned short* w1h  = (unsigned short*)(ws + OFF_W1H);
    unsigned short* wi2h = (unsigned short*)(ws + OFF_WI2H);
    unsigned short* wh2h = (unsigned short*)(ws + OFF_WH2H);
    float* h2a  = ws + OFF_H2A;
    float* dold = ws + OFF_DOLD;
    float* dh   = ws + OFF_DH;
    float* mt   = ws + OFF_MT;
    float* st   = ws + OFF_ST;

    static bool attr_set = false;
    (void)attr_set;
    hipFuncSetAttribute((const void*)k1_lstm,
                        hipFuncAttributeMaxDynamicSharedMemorySize, K1_LDS_B);

    k0_prep<<<dim3((G4 * HH + 255) / 256), dim3(256), 0, stream>>>(
        Whh1, Wih2, Whh2, fcW, fcWT, w1h, wi2h, wh2h);

    k1_lstm<<<dim3(BB), dim3(512), K1_LDS_B, stream>>>(
        x, Wih1, bih1, bhh1, bih2, bhh2, w1h, wi2h, wh2h, h2a);

    k2_dots<<<dim3(256), dim3(256), 0, stream>>>(h2a, w_t, dold, dh);

    k3_stats<<<dim3(TT), dim3(256), 0, stream>>>(dold, dh, mt, st);

    k4_attn<<<dim3(BB), dim3(128), 0, stream>>>(h2a, dold, dh, mt, st);

    k5_fc<<<dim3(TT, BB / 32), dim3(256), 0, stream>>>(h2a, fcWT, fcb, out);
}

// Round 5
// 1514.008 us; speedup vs baseline: 8.4223x; 1.0138x over previous
//
#include <hip/hip_runtime.h>
#include <math.h>

#define BB 128
#define TT 512
#define HH 128
#define G4 512      // 4*H
#define CC 128
#define WW 32

// ---- workspace layout (float slots) ----
#define OFF_FCWT  0                          // 16384
#define OFF_W1P   (OFF_FCWT + CC*HH)         // f16 permuted Whh1: 32768 slots
#define OFF_WI2P  (OFF_W1P  + G4*HH/2)
#define OFF_WH2P  (OFF_WI2P + G4*HH/2)
#define OFF_B1P   (OFF_WH2P + G4*HH/2)       // 512
#define OFF_WI1P  (OFF_B1P + G4)
#define OFF_B2P   (OFF_WI1P + G4)
#define OFF_H2A   (OFF_B2P + G4)             // [T][B][H] fp32, later y in-place
#define OFF_DOLD  (OFF_H2A + TT*BB*HH)
#define OFF_DH    (OFF_DOLD + TT*BB)
#define OFF_MT    (OFF_DH + TT*BB)
#define OFF_ST    (OFF_MT + TT)

typedef _Float16 h2t __attribute__((ext_vector_type(2)));

__device__ __forceinline__ float sigm(float v) {
    return 1.f / (1.f + __expf(-v));
}
__device__ __forceinline__ float ftanh(float v) {
    return 1.f - 2.f / (__expf(2.f * v) + 1.f);
}
__device__ __forceinline__ unsigned short f16b(float v) {
    return __builtin_bit_cast(unsigned short, (_Float16)v);
}
__device__ __forceinline__ float dot2f(unsigned int a, unsigned int b, float acc) {
#if defined(__has_builtin) && __has_builtin(__builtin_amdgcn_fdot2)
    return __builtin_amdgcn_fdot2(__builtin_bit_cast(h2t, a),
                                  __builtin_bit_cast(h2t, b), acc, false);
#else
    h2t av = __builtin_bit_cast(h2t, a), bv = __builtin_bit_cast(h2t, b);
    acc = fmaf((float)av.x, (float)bv.x, acc);
    acc = fmaf((float)av.y, (float)bv.y, acc);
    return acc;
#endif
}

// K0: gate-interleaved (r = h*4 + g) f16 weight images + permuted biases +
// fcW transpose. Permutation lets a 4-lane group own all 4 gates of one
// hidden unit -> cell update in registers, no LDS gate exchange.
__global__ __launch_bounds__(256) void k0_prep(
    const float* __restrict__ Whh1, const float* __restrict__ Wih2,
    const float* __restrict__ Whh2, const float* __restrict__ fcW,
    const float* __restrict__ Wih1,
    const float* __restrict__ bih1, const float* __restrict__ bhh1,
    const float* __restrict__ bih2, const float* __restrict__ bhh2,
    float* __restrict__ fcWT,
    unsigned short* __restrict__ w1p, unsigned short* __restrict__ wi2p,
    unsigned short* __restrict__ wh2p,
    float* __restrict__ b1p, float* __restrict__ wi1p, float* __restrict__ b2p)
{
    int idx = blockIdx.x * blockDim.x + threadIdx.x;
    if (idx < G4 * HH) {
        int r_old = idx >> 7, k = idx & 127;
        int g = r_old >> 7, h = r_old & 127;
        int dst = (h * 4 + g) * HH + k;
        w1p [dst] = f16b(Whh1[idx]);
        wi2p[dst] = f16b(Wih2[idx]);
        wh2p[dst] = f16b(Whh2[idx]);
    }
    if (idx < CC * HH) {
        int c = idx / HH, h = idx % HH;
        fcWT[h * CC + c] = fcW[idx];
    }
    if (idx < G4) {
        int g = idx >> 7, h = idx & 127;
        int rn = h * 4 + g;
        b1p [rn] = bih1[idx] + bhh1[idx];
        wi1p[rn] = Wih1[idx];
        b2p [rn] = bih2[idx] + bhh2[idx];
    }
}

// K1: all-register-weight LSTM. 128 blocks (1 batch) x 512 threads.
// Thread (r4 = tid>>2, s = tid&3) owns gates i,f,g,o of hidden unit r4 over
// k-slice [32s,32s+32). 192 VGPRs of f16 weights/thread (zero redundancy).
// Quad shfl_xor reduce (DPP) -> cell update in regs. Parity-double-buffered
// h/c vectors in LDS -> 2 barriers/step.
__global__ __launch_bounds__(512, 2) void k1_lstm(
    const float* __restrict__ x,
    const float* __restrict__ b1p, const float* __restrict__ wi1p,
    const float* __restrict__ b2p,
    const unsigned short* __restrict__ w1p,
    const unsigned short* __restrict__ wi2p,
    const unsigned short* __restrict__ wh2p,
    float* __restrict__ h2a)
{
    __shared__ __align__(16) unsigned int h1h[2][64];
    __shared__ __align__(16) unsigned int c1h[2][64];
    __shared__ __align__(16) unsigned int h2h[2][64];
    __shared__ float xs[TT];

    const int tid = threadIdx.x;
    const int b   = blockIdx.x;
    const int r4  = tid >> 2;       // hidden unit 0..127
    const int s   = tid & 3;        // k-slice: halves [32s, 32s+32)
    const int rbase = r4 * 4;

    // ---- weights: rows rbase..rbase+3, slice s -> 48 uint4 = 192 VGPRs ----
    uint4 w1[4][4], wi2[4][4], wh2[4][4];
    #pragma unroll
    for (int rr = 0; rr < 4; ++rr) {
        const uint4* p1 = (const uint4*)(w1p  + (size_t)(rbase + rr) * HH + 32 * s);
        const uint4* p2 = (const uint4*)(wi2p + (size_t)(rbase + rr) * HH + 32 * s);
        const uint4* p3 = (const uint4*)(wh2p + (size_t)(rbase + rr) * HH + 32 * s);
        #pragma unroll
        for (int q = 0; q < 4; ++q) { w1[rr][q] = p1[q]; wi2[rr][q] = p2[q]; wh2[rr][q] = p3[q]; }
    }
    float b1v[4], wi1v[4], b2v[4];
    #pragma unroll
    for (int rr = 0; rr < 4; ++rr) {
        b1v[rr]  = b1p [rbase + rr];
        wi1v[rr] = wi1p[rbase + rr];
        b2v[rr]  = b2p [rbase + rr];
    }

    xs[tid] = x[(size_t)b * TT + tid];
    if (tid < 64) { h1h[0][tid] = 0u; c1h[0][tid] = 0u; h2h[0][tid] = 0u; }
    float c1reg = 0.f, c2reg = 0.f;
    __syncthreads();

    float* outp = h2a + (size_t)b * HH + r4;

    for (int t = 0; t < TT; ++t) {
        const int p = t & 1, q = p ^ 1;
        const float xv = xs[t];

        // ---- phase 1: layer-1 gates + cell (reads h1h[p], writes [q]) ----
        {
            uint4 hv[4];
            #pragma unroll
            for (int qq = 0; qq < 4; ++qq)
                hv[qq] = *(const uint4*)&h1h[p][16 * s + 4 * qq];
            float a0 = 0.f, a1 = 0.f, a2 = 0.f, a3 = 0.f;
            #pragma unroll
            for (int qq = 0; qq < 4; ++qq) {
                uint4 h4 = hv[qq];
                a0 = dot2f(w1[0][qq].x, h4.x, a0); a0 = dot2f(w1[0][qq].y, h4.y, a0);
                a0 = dot2f(w1[0][qq].z, h4.z, a0); a0 = dot2f(w1[0][qq].w, h4.w, a0);
                a1 = dot2f(w1[1][qq].x, h4.x, a1); a1 = dot2f(w1[1][qq].y, h4.y, a1);
                a1 = dot2f(w1[1][qq].z, h4.z, a1); a1 = dot2f(w1[1][qq].w, h4.w, a1);
                a2 = dot2f(w1[2][qq].x, h4.x, a2); a2 = dot2f(w1[2][qq].y, h4.y, a2);
                a2 = dot2f(w1[2][qq].z, h4.z, a2); a2 = dot2f(w1[2][qq].w, h4.w, a2);
                a3 = dot2f(w1[3][qq].x, h4.x, a3); a3 = dot2f(w1[3][qq].y, h4.y, a3);
                a3 = dot2f(w1[3][qq].z, h4.z, a3); a3 = dot2f(w1[3][qq].w, h4.w, a3);
            }
            a0 += __shfl_xor(a0, 1); a0 += __shfl_xor(a0, 2);
            a1 += __shfl_xor(a1, 1); a1 += __shfl_xor(a1, 2);
            a2 += __shfl_xor(a2, 1); a2 += __shfl_xor(a2, 2);
            a3 += __shfl_xor(a3, 1); a3 += __shfl_xor(a3, 2);
            float gi = a0 + fmaf(xv, wi1v[0], b1v[0]);
            float gf = a1 + fmaf(xv, wi1v[1], b1v[1]);
            float gg = a2 + fmaf(xv, wi1v[2], b1v[2]);
            float go = a3 + fmaf(xv, wi1v[3], b1v[3]);
            float cn = sigm(gf) * c1reg + sigm(gi) * ftanh(gg);
            c1reg = cn;
            float hn = sigm(go) * ftanh(cn);
            if (s == 0) {
                ((unsigned short*)&h1h[q][0])[r4] = f16b(hn);
                ((unsigned short*)&c1h[q][0])[r4] = f16b(cn);
            }
        }
        __syncthreads();

        // ---- phase 2: layer-2 gates + cell (c1h[q], h2h[p] -> h2h[q]) ----
        {
            uint4 cv[4], gv[4];
            #pragma unroll
            for (int qq = 0; qq < 4; ++qq) {
                cv[qq] = *(const uint4*)&c1h[q][16 * s + 4 * qq];
                gv[qq] = *(const uint4*)&h2h[p][16 * s + 4 * qq];
            }
            float a0 = 0.f, a1 = 0.f, a2 = 0.f, a3 = 0.f;
            #pragma unroll
            for (int qq = 0; qq < 4; ++qq) {
                uint4 c4 = cv[qq], h4 = gv[qq];
                a0 = dot2f(wi2[0][qq].x, c4.x, a0); a0 = dot2f(wh2[0][qq].x, h4.x, a0);
                a0 = dot2f(wi2[0][qq].y, c4.y, a0); a0 = dot2f(wh2[0][qq].y, h4.y, a0);
                a0 = dot2f(wi2[0][qq].z, c4.z, a0); a0 = dot2f(wh2[0][qq].z, h4.z, a0);
                a0 = dot2f(wi2[0][qq].w, c4.w, a0); a0 = dot2f(wh2[0][qq].w, h4.w, a0);
                a1 = dot2f(wi2[1][qq].x, c4.x, a1); a1 = dot2f(wh2[1][qq].x, h4.x, a1);
                a1 = dot2f(wi2[1][qq].y, c4.y, a1); a1 = dot2f(wh2[1][qq].y, h4.y, a1);
                a1 = dot2f(wi2[1][qq].z, c4.z, a1); a1 = dot2f(wh2[1][qq].z, h4.z, a1);
                a1 = dot2f(wi2[1][qq].w, c4.w, a1); a1 = dot2f(wh2[1][qq].w, h4.w, a1);
                a2 = dot2f(wi2[2][qq].x, c4.x, a2); a2 = dot2f(wh2[2][qq].x, h4.x, a2);
                a2 = dot2f(wi2[2][qq].y, c4.y, a2); a2 = dot2f(wh2[2][qq].y, h4.y, a2);
                a2 = dot2f(wi2[2][qq].z, c4.z, a2); a2 = dot2f(wh2[2][qq].z, h4.z, a2);
                a2 = dot2f(wi2[2][qq].w, c4.w, a2); a2 = dot2f(wh2[2][qq].w, h4.w, a2);
                a3 = dot2f(wi2[3][qq].x, c4.x, a3); a3 = dot2f(wh2[3][qq].x, h4.x, a3);
                a3 = dot2f(wi2[3][qq].y, c4.y, a3); a3 = dot2f(wh2[3][qq].y, h4.y, a3);
                a3 = dot2f(wi2[3][qq].z, c4.z, a3); a3 = dot2f(wh2[3][qq].z, h4.z, a3);
                a3 = dot2f(wi2[3][qq].w, c4.w, a3); a3 = dot2f(wh2[3][qq].w, h4.w, a3);
            }
            a0 += __shfl_xor(a0, 1); a0 += __shfl_xor(a0, 2);
            a1 += __shfl_xor(a1, 1); a1 += __shfl_xor(a1, 2);
            a2 += __shfl_xor(a2, 1); a2 += __shfl_xor(a2, 2);
            a3 += __shfl_xor(a3, 1); a3 += __shfl_xor(a3, 2);
            float gi = a0 + b2v[0];
            float gf = a1 + b2v[1];
            float gg = a2 + b2v[2];
            float go = a3 + b2v[3];
            float cn = sigm(gf) * c2reg + sigm(gi) * ftanh(gg);
            c2reg = cn;
            float hn = sigm(go) * ftanh(cn);
            if (s == 0) {
                ((unsigned short*)&h2h[q][0])[r4] = f16b(hn);
                outp[(size_t)t * (BB * HH)] = hn;
            }
        }
        __syncthreads();
    }
}

// K2: d_old[t,b] = h2[t,b,:].wt_old ; d_h[t,b] = h2[t,b,:].wt_h
__global__ __launch_bounds__(256) void k2_dots(
    const float* __restrict__ h2a, const float* __restrict__ w_t,
    float* __restrict__ dold, float* __restrict__ dh)
{
    const int lane = threadIdx.x & 63;
    const int wave = blockIdx.x * (blockDim.x >> 6) + (threadIdx.x >> 6);
    const int nw = gridDim.x * (blockDim.x >> 6);
    const float wh0 = w_t[lane],       wh1 = w_t[64 + lane];
    const float wo0 = w_t[128 + lane], wo1 = w_t[192 + lane];
    for (int row = wave; row < TT * BB; row += nw) {
        const float* p = h2a + (size_t)row * HH;
        float v0 = p[lane], v1 = p[64 + lane];
        float po = v0 * wo0 + v1 * wo1;
        float ph = v0 * wh0 + v1 * wh1;
        #pragma unroll
        for (int off = 32; off; off >>= 1) {
            po += __shfl_xor(po, off);
            ph += __shfl_xor(ph, off);
        }
        if (lane == 0) { dold[row] = po; dh[row] = ph; }
    }
}

// K3: per-t global softmax stats over valid (j,b): m[t], s[t]
__global__ __launch_bounds__(256) void k3_stats(
    const float* __restrict__ dold, const float* __restrict__ dh,
    float* __restrict__ mt, float* __restrict__ st)
{
    const int t = blockIdx.x;
    const int tid = threadIdx.x;
    const int cnt = (min(t, WW) + 1) * BB;
    const int jstart = max(t - (WW + 1), -1);

    float m = -INFINITY;
    for (int idx = tid; idx < cnt; idx += 256) {
        int jj = idx >> 7, b = idx & 127;
        int j = jstart + jj;
        float sc = dh[t * BB + b] + (j >= 0 ? dold[j * BB + b] : 0.f);
        m = fmaxf(m, sc);
    }
    #pragma unroll
    for (int off = 32; off; off >>= 1) m = fmaxf(m, __shfl_xor(m, off));
    __shared__ float rbuf[4];
    int wv = tid >> 6, ln = tid & 63;
    if (ln == 0) rbuf[wv] = m;
    __syncthreads();
    m = fmaxf(fmaxf(rbuf[0], rbuf[1]), fmaxf(rbuf[2], rbuf[3]));

    float s = 0.f;
    for (int idx = tid; idx < cnt; idx += 256) {
        int jj = idx >> 7, b = idx & 127;
        int j = jstart + jj;
        float sc = dh[t * BB + b] + (j >= 0 ? dold[j * BB + b] : 0.f);
        s += __expf(sc - m);
    }
    #pragma unroll
    for (int off = 32; off; off >>= 1) s += __shfl_xor(s, off);
    __shared__ float sbuf[4];
    if (ln == 0) sbuf[wv] = s;
    __syncthreads();
    if (tid == 0) { mt[t] = m; st[t] = sbuf[0] + sbuf[1] + sbuf[2] + sbuf[3]; }
}

// K4: attention + y = h2 + attn, written IN-PLACE over h2a (sequential per
// batch; ring preloads history before overwrite -> in-place safe).
__global__ __launch_bounds__(128) void k4_attn(
    float* __restrict__ h2a,
    const float* __restrict__ dold, const float* __restrict__ dh,
    const float* __restrict__ mt, const float* __restrict__ st)
{
    const int b = blockIdx.x;
    const int h = threadIdx.x;
    __shared__ float ring[33][HH];
    __shared__ float wj[33];

    #pragma unroll
    for (int s_ = 0; s_ < 33; ++s_) ring[s_][h] = 0.f;
    __syncthreads();

    for (int t = 0; t < TT; ++t) {
        float hv = h2a[(size_t)t * (BB * HH) + b * HH + h];
        if (h < 33) {
            int j = t - 33 + h;
            float w = 0.f;
            if (j >= 0)
                w = __expf(dold[j * BB + b] + dh[t * BB + b] - mt[t]) / st[t];
            wj[h] = w;
        }
        __syncthreads();

        float acc = 0.f;
        const int r0 = t % 33;
        #pragma unroll
        for (int jj = 0; jj < 33; ++jj) {
            int rr = r0 + jj; if (rr >= 33) rr -= 33;
            acc = fmaf(wj[jj], ring[rr][h], acc);
        }
        __syncthreads();

        h2a[(size_t)t * (BB * HH) + b * HH + h] = hv + acc;
        ring[r0][h] = hv;
    }
}

// K5: out[b,t,c] = y[t,b,:].fcW[c,:] + fcb[c]
__global__ __launch_bounds__(256) void k5_fc(
    const float* __restrict__ y, const float* __restrict__ fcWT,
    const float* __restrict__ fcb, float* __restrict__ out)
{
    const int t  = blockIdx.x;
    const int b0 = blockIdx.y * 32;
    const int tid = threadIdx.x;
    __shared__ float ytile[32][HH];

    for (int i = tid; i < 32 * HH; i += 256) {
        int rr = i >> 7, hh = i & 127;
        ytile[rr][hh] = y[(size_t)t * (BB * HH) + (b0 + rr) * HH + hh];
    }
    __syncthreads();

    const int c  = tid & 127;
    const int rh = tid >> 7;
    float acc[16];
    const float bias = fcb[c];
    #pragma unroll
    for (int rr = 0; rr < 16; ++rr) acc[rr] = bias;

    for (int hh = 0; hh < HH; ++hh) {
        float w = fcWT[hh * CC + c];
        #pragma unroll
        for (int rr = 0; rr < 16; ++rr)
            acc[rr] = fmaf(ytile[rh * 16 + rr][hh], w, acc[rr]);
    }
    #pragma unroll
    for (int rr = 0; rr < 16; ++rr) {
        int b = b0 + rh * 16 + rr;
        out[(size_t)b * (TT * CC) + t * CC + c] = acc[rr];
    }
}

extern "C" void kernel_launch(void* const* d_in, const int* in_sizes, int n_in,
                              void* d_out, int out_size, void* d_ws, size_t ws_size,
                              hipStream_t stream)
{
    const float* x    = (const float*)d_in[0];
    const float* Wih1 = (const float*)d_in[1];
    const float* Whh1 = (const float*)d_in[2];
    const float* bih1 = (const float*)d_in[3];
    const float* bhh1 = (const float*)d_in[4];
    const float* Wih2 = (const float*)d_in[5];
    const float* Whh2 = (const float*)d_in[6];
    const float* bih2 = (const float*)d_in[7];
    const float* bhh2 = (const float*)d_in[8];
    const float* w_t  = (const float*)d_in[9];
    const float* fcW  = (const float*)d_in[10];
    const float* fcb  = (const float*)d_in[11];
    float* out = (float*)d_out;

    float* ws   = (float*)d_ws;
    float* fcWT = ws + OFF_FCWT;
    unsigned short* w1p  = (unsigned short*)(ws + OFF_W1P);
    unsigned short* wi2p = (unsigned short*)(ws + OFF_WI2P);
    unsigned short* wh2p = (unsigned short*)(ws + OFF_WH2P);
    float* b1pp = ws + OFF_B1P;
    float* wi1p = ws + OFF_WI1P;
    float* b2pp = ws + OFF_B2P;
    float* h2a  = ws + OFF_H2A;
    float* dold = ws + OFF_DOLD;
    float* dh   = ws + OFF_DH;
    float* mt   = ws + OFF_MT;
    float* st   = ws + OFF_ST;

    k0_prep<<<dim3((G4 * HH + 255) / 256), dim3(256), 0, stream>>>(
        Whh1, Wih2, Whh2, fcW, Wih1, bih1, bhh1, bih2, bhh2,
        fcWT, w1p, wi2p, wh2p, b1pp, wi1p, b2pp);

    k1_lstm<<<dim3(BB), dim3(512), 0, stream>>>(
        x, b1pp, wi1p, b2pp, w1p, wi2p, wh2p, h2a);

    k2_dots<<<dim3(256), dim3(256), 0, stream>>>(h2a, w_t, dold, dh);

    k3_stats<<<dim3(TT), dim3(256), 0, stream>>>(dold, dh, mt, st);

    k4_attn<<<dim3(BB), dim3(128), 0, stream>>>(h2a, dold, dh, mt, st);

    k5_fc<<<dim3(TT, BB / 32), dim3(256), 0, stream>>>(h2a, fcWT, fcb, out);
}

// Round 6
// 1089.224 us; speedup vs baseline: 11.7069x; 1.3900x over previous
//
#include <hip/hip_runtime.h>
#include <math.h>

#define BB 128
#define TT 512
#define HH 128
#define G4 512      // 4*H
#define CC 128
#define WW 32

// ---- workspace layout (float slots) ----
#define OFF_FCWT  0                          // 16384
#define OFF_W1P   (OFF_FCWT + CC*HH)         // f16 permuted Whh1: 32768 slots
#define OFF_WI2P  (OFF_W1P  + G4*HH/2)
#define OFF_WH2P  (OFF_WI2P + G4*HH/2)
#define OFF_B1P   (OFF_WH2P + G4*HH/2)       // 512
#define OFF_WI1P  (OFF_B1P + G4)
#define OFF_B2P   (OFF_WI1P + G4)
#define OFF_H2A   (OFF_B2P + G4)             // [T][B][H] fp32 (read-only after k1)
#define OFF_DOLD  (OFF_H2A + TT*BB*HH)
#define OFF_DH    (OFF_DOLD + TT*BB)
#define OFF_MT    (OFF_DH + TT*BB)
#define OFF_ST    (OFF_MT + TT)

typedef _Float16 h2t __attribute__((ext_vector_type(2)));

__device__ __forceinline__ float sigm(float v) {
    return 1.f / (1.f + __expf(-v));
}
__device__ __forceinline__ float ftanh(float v) {
    return 1.f - 2.f / (__expf(2.f * v) + 1.f);
}
__device__ __forceinline__ unsigned short f16b(float v) {
    return __builtin_bit_cast(unsigned short, (_Float16)v);
}
__device__ __forceinline__ float dot2f(unsigned int a, unsigned int b, float acc) {
#if defined(__has_builtin) && __has_builtin(__builtin_amdgcn_fdot2)
    return __builtin_amdgcn_fdot2(__builtin_bit_cast(h2t, a),
                                  __builtin_bit_cast(h2t, b), acc, false);
#else
    h2t av = __builtin_bit_cast(h2t, a), bv = __builtin_bit_cast(h2t, b);
    acc = fmaf((float)av.x, (float)bv.x, acc);
    acc = fmaf((float)av.y, (float)bv.y, acc);
    return acc;
#endif
}

// K0: gate-interleaved (r = h*4 + g) f16 weight images + permuted biases +
// fcW transpose.
__global__ __launch_bounds__(256) void k0_prep(
    const float* __restrict__ Whh1, const float* __restrict__ Wih2,
    const float* __restrict__ Whh2, const float* __restrict__ fcW,
    const float* __restrict__ Wih1,
    const float* __restrict__ bih1, const float* __restrict__ bhh1,
    const float* __restrict__ bih2, const float* __restrict__ bhh2,
    float* __restrict__ fcWT,
    unsigned short* __restrict__ w1p, unsigned short* __restrict__ wi2p,
    unsigned short* __restrict__ wh2p,
    float* __restrict__ b1p, float* __restrict__ wi1p, float* __restrict__ b2p)
{
    int idx = blockIdx.x * blockDim.x + threadIdx.x;
    if (idx < G4 * HH) {
        int r_old = idx >> 7, k = idx & 127;
        int g = r_old >> 7, h = r_old & 127;
        int dst = (h * 4 + g) * HH + k;
        w1p [dst] = f16b(Whh1[idx]);
        wi2p[dst] = f16b(Wih2[idx]);
        wh2p[dst] = f16b(Whh2[idx]);
    }
    if (idx < CC * HH) {
        int c = idx / HH, h = idx % HH;
        fcWT[h * CC + c] = fcW[idx];
    }
    if (idx < G4) {
        int g = idx >> 7, h = idx & 127;
        int rn = h * 4 + g;
        b1p [rn] = bih1[idx] + bhh1[idx];
        wi1p[rn] = Wih1[idx];
        b2p [rn] = bih2[idx] + bhh2[idx];
    }
}

// K1: software-pipelined all-register-weight LSTM. 128 blocks x 512 threads.
// Iteration u computes layer-1(t=u) AND layer-2(t=u-1) in one slab (layer-2
// lags one step: needs only c1(u-1), h2(u-2)), then both cell updates, then
// ONE barrier (parity double-buffered state vectors).
__global__ __launch_bounds__(512, 2) void k1_lstm(
    const float* __restrict__ x,
    const float* __restrict__ b1p, const float* __restrict__ wi1p,
    const float* __restrict__ b2p,
    const unsigned short* __restrict__ w1p,
    const unsigned short* __restrict__ wi2p,
    const unsigned short* __restrict__ wh2p,
    float* __restrict__ h2a)
{
    __shared__ __align__(16) unsigned int h1h[2][64];
    __shared__ __align__(16) unsigned int c1h[2][64];
    __shared__ __align__(16) unsigned int h2h[2][64];
    __shared__ float xs[TT];

    const int tid = threadIdx.x;
    const int b   = blockIdx.x;
    const int r4  = tid >> 2;       // hidden unit 0..127
    const int s   = tid & 3;        // k-slice: halves [32s, 32s+32)
    const int rbase = r4 * 4;

    // ---- weights: rows rbase..rbase+3, slice s -> 48 uint4 = 192 regs ----
    uint4 w1[4][4], wi2[4][4], wh2[4][4];
    #pragma unroll
    for (int rr = 0; rr < 4; ++rr) {
        const uint4* p1 = (const uint4*)(w1p  + (size_t)(rbase + rr) * HH + 32 * s);
        const uint4* p2 = (const uint4*)(wi2p + (size_t)(rbase + rr) * HH + 32 * s);
        const uint4* p3 = (const uint4*)(wh2p + (size_t)(rbase + rr) * HH + 32 * s);
        #pragma unroll
        for (int q = 0; q < 4; ++q) { w1[rr][q] = p1[q]; wi2[rr][q] = p2[q]; wh2[rr][q] = p3[q]; }
    }
    float b1v[4], wi1v[4], b2v[4];
    #pragma unroll
    for (int rr = 0; rr < 4; ++rr) {
        b1v[rr]  = b1p [rbase + rr];
        wi1v[rr] = wi1p[rbase + rr];
        b2v[rr]  = b2p [rbase + rr];
    }

    xs[tid] = x[(size_t)b * TT + tid];
    if (tid < 64) {
        h1h[0][tid] = 0u; c1h[0][tid] = 0u; h2h[0][tid] = 0u;
        h1h[1][tid] = 0u; c1h[1][tid] = 0u; h2h[1][tid] = 0u;
    }
    float c1reg = 0.f, c2reg = 0.f;
    __syncthreads();

    float* outp = h2a + (size_t)b * HH + r4;

    // ---- prologue u=0: layer-1 only, h1(prev)=0 -> gates are scalar ----
    {
        const float xv = xs[0];
        float gi = fmaf(xv, wi1v[0], b1v[0]);
        float gf = fmaf(xv, wi1v[1], b1v[1]);
        float gg = fmaf(xv, wi1v[2], b1v[2]);
        float go = fmaf(xv, wi1v[3], b1v[3]);
        float cn = sigm(gf) * 0.f + sigm(gi) * ftanh(gg);
        c1reg = cn;
        float hn = sigm(go) * ftanh(cn);
        if (s == 0) {                     // q for u=0 is 1
            ((unsigned short*)&h1h[1][0])[r4] = f16b(hn);
            ((unsigned short*)&c1h[1][0])[r4] = f16b(cn);
        }
    }
    __syncthreads();

    // ---- main: u = 1 .. TT-1 ----
    for (int u = 1; u < TT; ++u) {
        const int p = u & 1, q = p ^ 1;
        const float xv = xs[u];

        // dots layer-1 (t=u): h1h[p] = h1(u-1)
        float a0 = 0.f, a1 = 0.f, a2 = 0.f, a3 = 0.f;
        {
            #pragma unroll
            for (int qq = 0; qq < 4; ++qq) {
                uint4 h4 = *(const uint4*)&h1h[p][16 * s + 4 * qq];
                a0 = dot2f(w1[0][qq].x, h4.x, a0); a0 = dot2f(w1[0][qq].y, h4.y, a0);
                a0 = dot2f(w1[0][qq].z, h4.z, a0); a0 = dot2f(w1[0][qq].w, h4.w, a0);
                a1 = dot2f(w1[1][qq].x, h4.x, a1); a1 = dot2f(w1[1][qq].y, h4.y, a1);
                a1 = dot2f(w1[1][qq].z, h4.z, a1); a1 = dot2f(w1[1][qq].w, h4.w, a1);
                a2 = dot2f(w1[2][qq].x, h4.x, a2); a2 = dot2f(w1[2][qq].y, h4.y, a2);
                a2 = dot2f(w1[2][qq].z, h4.z, a2); a2 = dot2f(w1[2][qq].w, h4.w, a2);
                a3 = dot2f(w1[3][qq].x, h4.x, a3); a3 = dot2f(w1[3][qq].y, h4.y, a3);
                a3 = dot2f(w1[3][qq].z, h4.z, a3); a3 = dot2f(w1[3][qq].w, h4.w, a3);
            }
        }
        // dots layer-2 (t=u-1): c1h[p] = c1(u-1), h2h[p] = h2(u-2)
        float d0 = 0.f, d1 = 0.f, d2 = 0.f, d3 = 0.f;
        {
            #pragma unroll
            for (int qq = 0; qq < 4; ++qq) {
                uint4 c4 = *(const uint4*)&c1h[p][16 * s + 4 * qq];
                uint4 h4 = *(const uint4*)&h2h[p][16 * s + 4 * qq];
                d0 = dot2f(wi2[0][qq].x, c4.x, d0); d0 = dot2f(wh2[0][qq].x, h4.x, d0);
                d0 = dot2f(wi2[0][qq].y, c4.y, d0); d0 = dot2f(wh2[0][qq].y, h4.y, d0);
                d0 = dot2f(wi2[0][qq].z, c4.z, d0); d0 = dot2f(wh2[0][qq].z, h4.z, d0);
                d0 = dot2f(wi2[0][qq].w, c4.w, d0); d0 = dot2f(wh2[0][qq].w, h4.w, d0);
                d1 = dot2f(wi2[1][qq].x, c4.x, d1); d1 = dot2f(wh2[1][qq].x, h4.x, d1);
                d1 = dot2f(wi2[1][qq].y, c4.y, d1); d1 = dot2f(wh2[1][qq].y, h4.y, d1);
                d1 = dot2f(wi2[1][qq].z, c4.z, d1); d1 = dot2f(wh2[1][qq].z, h4.z, d1);
                d1 = dot2f(wi2[1][qq].w, c4.w, d1); d1 = dot2f(wh2[1][qq].w, h4.w, d1);
                d2 = dot2f(wi2[2][qq].x, c4.x, d2); d2 = dot2f(wh2[2][qq].x, h4.x, d2);
                d2 = dot2f(wi2[2][qq].y, c4.y, d2); d2 = dot2f(wh2[2][qq].y, h4.y, d2);
                d2 = dot2f(wi2[2][qq].z, c4.z, d2); d2 = dot2f(wh2[2][qq].z, h4.z, d2);
                d2 = dot2f(wi2[2][qq].w, c4.w, d2); d2 = dot2f(wh2[2][qq].w, h4.w, d2);
                d3 = dot2f(wi2[3][qq].x, c4.x, d3); d3 = dot2f(wh2[3][qq].x, h4.x, d3);
                d3 = dot2f(wi2[3][qq].y, c4.y, d3); d3 = dot2f(wh2[3][qq].y, h4.y, d3);
                d3 = dot2f(wi2[3][qq].z, c4.z, d3); d3 = dot2f(wh2[3][qq].z, h4.z, d3);
                d3 = dot2f(wi2[3][qq].w, c4.w, d3); d3 = dot2f(wh2[3][qq].w, h4.w, d3);
            }
        }
        // quad reductions (8 accs)
        a0 += __shfl_xor(a0, 1); a0 += __shfl_xor(a0, 2);
        a1 += __shfl_xor(a1, 1); a1 += __shfl_xor(a1, 2);
        a2 += __shfl_xor(a2, 1); a2 += __shfl_xor(a2, 2);
        a3 += __shfl_xor(a3, 1); a3 += __shfl_xor(a3, 2);
        d0 += __shfl_xor(d0, 1); d0 += __shfl_xor(d0, 2);
        d1 += __shfl_xor(d1, 1); d1 += __shfl_xor(d1, 2);
        d2 += __shfl_xor(d2, 1); d2 += __shfl_xor(d2, 2);
        d3 += __shfl_xor(d3, 1); d3 += __shfl_xor(d3, 2);

        // cell-1 (t=u)
        {
            float gi = a0 + fmaf(xv, wi1v[0], b1v[0]);
            float gf = a1 + fmaf(xv, wi1v[1], b1v[1]);
            float gg = a2 + fmaf(xv, wi1v[2], b1v[2]);
            float go = a3 + fmaf(xv, wi1v[3], b1v[3]);
            float cn = sigm(gf) * c1reg + sigm(gi) * ftanh(gg);
            c1reg = cn;
            float hn = sigm(go) * ftanh(cn);
            if (s == 0) {
                ((unsigned short*)&h1h[q][0])[r4] = f16b(hn);
                ((unsigned short*)&c1h[q][0])[r4] = f16b(cn);
            }
        }
        // cell-2 (t=u-1)
        {
            float gi = d0 + b2v[0];
            float gf = d1 + b2v[1];
            float gg = d2 + b2v[2];
            float go = d3 + b2v[3];
            float cn = sigm(gf) * c2reg + sigm(gi) * ftanh(gg);
            c2reg = cn;
            float hn = sigm(go) * ftanh(cn);
            if (s == 0) {
                ((unsigned short*)&h2h[q][0])[r4] = f16b(hn);
                outp[(size_t)(u - 1) * (BB * HH)] = hn;
            }
        }
        __syncthreads();
    }

    // ---- epilogue u=TT: layer-2 only (t=TT-1). p = TT&1 = 0 ----
    {
        float d0 = 0.f, d1 = 0.f, d2 = 0.f, d3 = 0.f;
        #pragma unroll
        for (int qq = 0; qq < 4; ++qq) {
            uint4 c4 = *(const uint4*)&c1h[0][16 * s + 4 * qq];
            uint4 h4 = *(const uint4*)&h2h[0][16 * s + 4 * qq];
            d0 = dot2f(wi2[0][qq].x, c4.x, d0); d0 = dot2f(wh2[0][qq].x, h4.x, d0);
            d0 = dot2f(wi2[0][qq].y, c4.y, d0); d0 = dot2f(wh2[0][qq].y, h4.y, d0);
            d0 = dot2f(wi2[0][qq].z, c4.z, d0); d0 = dot2f(wh2[0][qq].z, h4.z, d0);
            d0 = dot2f(wi2[0][qq].w, c4.w, d0); d0 = dot2f(wh2[0][qq].w, h4.w, d0);
            d1 = dot2f(wi2[1][qq].x, c4.x, d1); d1 = dot2f(wh2[1][qq].x, h4.x, d1);
            d1 = dot2f(wi2[1][qq].y, c4.y, d1); d1 = dot2f(wh2[1][qq].y, h4.y, d1);
            d1 = dot2f(wi2[1][qq].z, c4.z, d1); d1 = dot2f(wh2[1][qq].z, h4.z, d1);
            d1 = dot2f(wi2[1][qq].w, c4.w, d1); d1 = dot2f(wh2[1][qq].w, h4.w, d1);
            d2 = dot2f(wi2[2][qq].x, c4.x, d2); d2 = dot2f(wh2[2][qq].x, h4.x, d2);
            d2 = dot2f(wi2[2][qq].y, c4.y, d2); d2 = dot2f(wh2[2][qq].y, h4.y, d2);
            d2 = dot2f(wi2[2][qq].z, c4.z, d2); d2 = dot2f(wh2[2][qq].z, h4.z, d2);
            d2 = dot2f(wi2[2][qq].w, c4.w, d2); d2 = dot2f(wh2[2][qq].w, h4.w, d2);
            d3 = dot2f(wi2[3][qq].x, c4.x, d3); d3 = dot2f(wh2[3][qq].x, h4.x, d3);
            d3 = dot2f(wi2[3][qq].y, c4.y, d3); d3 = dot2f(wh2[3][qq].y, h4.y, d3);
            d3 = dot2f(wi2[3][qq].z, c4.z, d3); d3 = dot2f(wh2[3][qq].z, h4.z, d3);
            d3 = dot2f(wi2[3][qq].w, c4.w, d3); d3 = dot2f(wh2[3][qq].w, h4.w, d3);
        }
        d0 += __shfl_xor(d0, 1); d0 += __shfl_xor(d0, 2);
        d1 += __shfl_xor(d1, 1); d1 += __shfl_xor(d1, 2);
        d2 += __shfl_xor(d2, 1); d2 += __shfl_xor(d2, 2);
        d3 += __shfl_xor(d3, 1); d3 += __shfl_xor(d3, 2);
        float gi = d0 + b2v[0];
        float gf = d1 + b2v[1];
        float gg = d2 + b2v[2];
        float go = d3 + b2v[3];
        float cn = sigm(gf) * c2reg + sigm(gi) * ftanh(gg);
        float hn = sigm(go) * ftanh(cn);
        if (s == 0) outp[(size_t)(TT - 1) * (BB * HH)] = hn;
    }
}

// K2: d_old[t,b] = h2[t,b,:].wt_old ; d_h[t,b] = h2[t,b,:].wt_h
__global__ __launch_bounds__(256) void k2_dots(
    const float* __restrict__ h2a, const float* __restrict__ w_t,
    float* __restrict__ dold, float* __restrict__ dh)
{
    const int lane = threadIdx.x & 63;
    const int wave = blockIdx.x * (blockDim.x >> 6) + (threadIdx.x >> 6);
    const int nw = gridDim.x * (blockDim.x >> 6);
    const float wh0 = w_t[lane],       wh1 = w_t[64 + lane];
    const float wo0 = w_t[128 + lane], wo1 = w_t[192 + lane];
    for (int row = wave; row < TT * BB; row += nw) {
        const float* p = h2a + (size_t)row * HH;
        float v0 = p[lane], v1 = p[64 + lane];
        float po = v0 * wo0 + v1 * wo1;
        float ph = v0 * wh0 + v1 * wh1;
        #pragma unroll
        for (int off = 32; off; off >>= 1) {
            po += __shfl_xor(po, off);
            ph += __shfl_xor(ph, off);
        }
        if (lane == 0) { dold[row] = po; dh[row] = ph; }
    }
}

// K3: per-t global softmax stats over valid (j,b): m[t], s[t]
__global__ __launch_bounds__(256) void k3_stats(
    const float* __restrict__ dold, const float* __restrict__ dh,
    float* __restrict__ mt, float* __restrict__ st)
{
    const int t = blockIdx.x;
    const int tid = threadIdx.x;
    const int cnt = (min(t, WW) + 1) * BB;
    const int jstart = max(t - (WW + 1), -1);

    float m = -INFINITY;
    for (int idx = tid; idx < cnt; idx += 256) {
        int jj = idx >> 7, b = idx & 127;
        int j = jstart + jj;
        float sc = dh[t * BB + b] + (j >= 0 ? dold[j * BB + b] : 0.f);
        m = fmaxf(m, sc);
    }
    #pragma unroll
    for (int off = 32; off; off >>= 1) m = fmaxf(m, __shfl_xor(m, off));
    __shared__ float rbuf[4];
    int wv = tid >> 6, ln = tid & 63;
    if (ln == 0) rbuf[wv] = m;
    __syncthreads();
    m = fmaxf(fmaxf(rbuf[0], rbuf[1]), fmaxf(rbuf[2], rbuf[3]));

    float s = 0.f;
    for (int idx = tid; idx < cnt; idx += 256) {
        int jj = idx >> 7, b = idx & 127;
        int j = jstart + jj;
        float sc = dh[t * BB + b] + (j >= 0 ? dold[j * BB + b] : 0.f);
        s += __expf(sc - m);
    }
    #pragma unroll
    for (int off = 32; off; off >>= 1) s += __shfl_xor(s, off);
    __shared__ float sbuf[4];
    if (ln == 0) sbuf[wv] = s;
    __syncthreads();
    if (tid == 0) { mt[t] = m; st[t] = sbuf[0] + sbuf[1] + sbuf[2] + sbuf[3]; }
}

// K45: fused attention + FC. grid (TT/8, BB), block 256.
// Loads h2 rows [t0-33, t0+8) into LDS, builds the 8x33 softmax weights,
// computes y = h2 + attn into LDS, then out[b,t,:] = y . fcW^T + fcb.
// h2a is never written -> no in-place race between t-tiles.
__global__ __launch_bounds__(256) void k45_attn_fc(
    const float* __restrict__ h2a,
    const float* __restrict__ dold, const float* __restrict__ dh,
    const float* __restrict__ mt, const float* __restrict__ st,
    const float* __restrict__ fcWT, const float* __restrict__ fcb,
    float* __restrict__ out)
{
    const int t0 = blockIdx.x * 8;
    const int b  = blockIdx.y;
    const int tid = threadIdx.x;

    __shared__ float hbuf[41][HH];     // rows t0-33 .. t0+7
    __shared__ float wjs[8][36];
    __shared__ float ytile[8][HH];

    // load 41 rows x 128 floats (float4), zeros for t<0
    for (int i = tid; i < 41 * 32; i += 256) {
        int r = i >> 5, q4 = i & 31;
        int t = t0 - 33 + r;
        float4 v = make_float4(0.f, 0.f, 0.f, 0.f);
        if (t >= 0)
            v = *(const float4*)(h2a + (size_t)t * (BB * HH) + (size_t)b * HH + q4 * 4);
        *(float4*)&hbuf[r][q4 * 4] = v;
    }
    // softmax weights: wjs[tt][ss] for t = t0+tt, j = t-33+ss
    for (int i = tid; i < 8 * 33; i += 256) {
        int tt = i / 33, ss = i % 33;
        int t = t0 + tt, j = t - 33 + ss;
        float w = 0.f;
        if (j >= 0)
            w = __expf(dold[j * BB + b] + dh[t * BB + b] - mt[t]) / st[t];
        wjs[tt][ss] = w;
    }
    __syncthreads();

    // attn: thread -> (tq = tid>>5, 4 h's at hq)
    {
        const int tq = tid >> 5;
        const int hq = (tid & 31) * 4;
        float4 acc = *(const float4*)&hbuf[tq + 33][hq];   // h2[t]
        #pragma unroll 11
        for (int ss = 0; ss < 33; ++ss) {
            float w = wjs[tq][ss];
            float4 hb = *(const float4*)&hbuf[tq + ss][hq];
            acc.x = fmaf(w, hb.x, acc.x);
            acc.y = fmaf(w, hb.y, acc.y);
            acc.z = fmaf(w, hb.z, acc.z);
            acc.w = fmaf(w, hb.w, acc.w);
        }
        *(float4*)&ytile[tq][hq] = acc;
    }
    __syncthreads();

    // FC: thread -> (c = tid&127, th = tid>>7 covers 4 t's)
    {
        const int c  = tid & 127;
        const int th = tid >> 7;
        float acc[4];
        const float bias = fcb[c];
        #pragma unroll
        for (int i = 0; i < 4; ++i) acc[i] = bias;
        for (int hh = 0; hh < HH; ++hh) {
            float w = fcWT[hh * CC + c];
            #pragma unroll
            for (int i = 0; i < 4; ++i)
                acc[i] = fmaf(ytile[th * 4 + i][hh], w, acc[i]);
        }
        #pragma unroll
        for (int i = 0; i < 4; ++i) {
            int t = t0 + th * 4 + i;
            out[(size_t)b * (TT * CC) + (size_t)t * CC + c] = acc[i];
        }
    }
}

extern "C" void kernel_launch(void* const* d_in, const int* in_sizes, int n_in,
                              void* d_out, int out_size, void* d_ws, size_t ws_size,
                              hipStream_t stream)
{
    const float* x    = (const float*)d_in[0];
    const float* Wih1 = (const float*)d_in[1];
    const float* Whh1 = (const float*)d_in[2];
    const float* bih1 = (const float*)d_in[3];
    const float* bhh1 = (const float*)d_in[4];
    const float* Wih2 = (const float*)d_in[5];
    const float* Whh2 = (const float*)d_in[6];
    const float* bih2 = (const float*)d_in[7];
    const float* bhh2 = (const float*)d_in[8];
    const float* w_t  = (const float*)d_in[9];
    const float* fcW  = (const float*)d_in[10];
    const float* fcb  = (const float*)d_in[11];
    float* out = (float*)d_out;

    float* ws   = (float*)d_ws;
    float* fcWT = ws + OFF_FCWT;
    unsigned short* w1p  = (unsigned short*)(ws + OFF_W1P);
    unsigned short* wi2p = (unsigned short*)(ws + OFF_WI2P);
    unsigned short* wh2p = (unsigned short*)(ws + OFF_WH2P);
    float* b1pp = ws + OFF_B1P;
    float* wi1p = ws + OFF_WI1P;
    float* b2pp = ws + OFF_B2P;
    float* h2a  = ws + OFF_H2A;
    float* dold = ws + OFF_DOLD;
    float* dh   = ws + OFF_DH;
    float* mt   = ws + OFF_MT;
    float* st   = ws + OFF_ST;

    k0_prep<<<dim3((G4 * HH + 255) / 256), dim3(256), 0, stream>>>(
        Whh1, Wih2, Whh2, fcW, Wih1, bih1, bhh1, bih2, bhh2,
        fcWT, w1p, wi2p, wh2p, b1pp, wi1p, b2pp);

    k1_lstm<<<dim3(BB), dim3(512), 0, stream>>>(
        x, b1pp, wi1p, b2pp, w1p, wi2p, wh2p, h2a);

    k2_dots<<<dim3(256), dim3(256), 0, stream>>>(h2a, w_t, dold, dh);

    k3_stats<<<dim3(TT), dim3(256), 0, stream>>>(dold, dh, mt, st);

    k45_attn_fc<<<dim3(TT / 8, BB), dim3(256), 0, stream>>>(
        h2a, dold, dh, mt, st, fcWT, fcb, out);
}